// Round 2
// baseline (829.398 us; speedup 1.0000x reference)
//
#include <hip/hip_runtime.h>
#include <hip/hip_bf16.h>
#include <stdint.h>

// ---------------------------------------------------------------------------
// AdaptiveAngleConv: 5 angles of (bilinear deform-sample -> 3x3 conv)
// x: (2,256,64,64) f32, weight: (256,256,3,3) f32
// out: 5 x (2,256,190,190) f32 concatenated
// Conv = implicit GEMM, BM=256px x BN=256oc, BK=32, 4-deep LDS ring,
// counted vmcnt(4), raw barriers, setprio around MFMA (T3+T4+T5).
// ---------------------------------------------------------------------------

#define S2F 1.41421356237309515f

__constant__ float c_ox[5][9] = {
  {0.f,0.f,0.f,0.f,0.f,0.f,0.f,0.f,0.f},
  {1.f-S2F, 1.f-S2F*0.5f, 1.f, -S2F*0.5f, 0.f, S2F*0.5f, -1.f, S2F*0.5f-1.f, S2F-1.f},
  {0.f,1.f,2.f,-1.f,0.f,1.f,-2.f,-1.f,0.f},
  {1.f, 1.f+S2F*0.5f, 1.f+S2F, -S2F*0.5f, 0.f, S2F*0.5f, -1.f-S2F, -1.f-S2F*0.5f, -1.f},
  {2.f,2.f,2.f,0.f,0.f,0.f,-2.f,-2.f,-2.f}
};
__constant__ float c_oy[5][9] = {
  {0.f,0.f,0.f,0.f,0.f,0.f,0.f,0.f,0.f},
  {1.f, S2F*0.5f, S2F-1.f, 1.f-S2F*0.5f, 0.f, S2F*0.5f-1.f, 1.f-S2F, -S2F*0.5f, -1.f},
  {2.f,1.f,0.f,1.f,0.f,-1.f,0.f,-1.f,-2.f},
  {1.f+S2F, S2F*0.5f, -1.f, 1.f+S2F*0.5f, 0.f, -1.f-S2F*0.5f, 1.f, -S2F*0.5f, 1.f+S2F},
  {2.f,0.f,-2.f,2.f,0.f,-2.f,2.f,0.f,-2.f}
};

typedef __bf16 bf16x8_t __attribute__((ext_vector_type(8)));
typedef float f32x4_t __attribute__((ext_vector_type(4)));

typedef const __attribute__((address_space(1))) void* as1cp;
typedef __attribute__((address_space(3))) void* as3p;

__device__ __forceinline__ void gload16(const void* g, void* l) {
  __builtin_amdgcn_global_load_lds((as1cp)g, (as3p)l, 16, 0, 0);
}

// x NCHW (2,256,64,64) -> xT NHWC (2,64,64,256) f32
__global__ void k_transpose(const float* __restrict__ x, float* __restrict__ xT) {
  const int v = blockIdx.x, u = blockIdx.y, b = blockIdx.z;
  const int ic = threadIdx.x;
  xT[(((b*64 + u)*64 + v)*256) + ic] =
      x[(((b*256 + ic)*64 + u)*64) + v];
}

// weight OIHW (256,256,3,3) f32 -> wb (9,256,256)=[t][oc][ic] bf16
__global__ void k_wconv(const float* __restrict__ w, __hip_bfloat16* __restrict__ wb) {
  const int tid = blockIdx.x*256 + threadIdx.x;   // < 9*256*256
  const int t = tid >> 16;
  const int rem = tid & 65535;
  const int oc = rem >> 8;
  const int ic = rem & 255;
  wb[tid] = __float2bfloat16(w[(oc*256 + ic)*9 + t]);
}

// bilinear deform-sample -> xo bf16 NHWC [(a)][b][192][192][256]
// grid (48, 192, nA): blockIdx.z selects angle (a0 + z); 4 ic per thread.
__global__ void k_sample(const float* __restrict__ xT,
                         __hip_bfloat16* __restrict__ xo, int a0)
{
  const int aidx = a0 + blockIdx.z;
  __hip_bfloat16* xoa = xo + (size_t)blockIdx.z * (2ull*192*192*256);

  const int tid = threadIdx.x;           // 256
  const int ic = (tid & 63) * 4;
  const int j = blockIdx.x*4 + (tid >> 6);
  const int i = blockIdx.y;

  const int a = i / 3, r = i - 3*a;
  const int bc = j / 3, s = j - 3*bc;
  const int n = r*3 + s;
  const float px = (float)(a + r) + c_ox[aidx][n];
  const float py = (float)(bc + s) + c_oy[aidx][n];
  const float fx = floorf(px), fy = floorf(py);
  const float pxc = fminf(fmaxf(px, 0.f), 65.f);
  const float pyc = fminf(fmaxf(py, 0.f), 65.f);
  const int qlx = (int)fminf(fmaxf(fx,      0.f), 65.f);
  const int qrx = (int)fminf(fmaxf(fx + 1.f, 0.f), 65.f);
  const int qly = (int)fminf(fmaxf(fy,      0.f), 65.f);
  const int qry = (int)fminf(fmaxf(fy + 1.f, 0.f), 65.f);
  const float wlx = 1.f + (float)qlx - pxc;
  const float wrx = 1.f - (float)qrx + pxc;
  const float wly = 1.f + (float)qly - pyc;
  const float wry = 1.f - (float)qry + pyc;
  const float glt = wlx*wly, grb = wrx*wry, glb = wlx*wry, grt = wrx*wly;

  const bool inxl = (qlx >= 1) && (qlx <= 64);
  const bool inxr = (qrx >= 1) && (qrx <= 64);
  const bool inyl = (qly >= 1) && (qly <= 64);
  const bool inyr = (qry >= 1) && (qry <= 64);

  const f32x4_t zero = (f32x4_t){0.f,0.f,0.f,0.f};
  #pragma unroll
  for (int b = 0; b < 2; ++b) {
    const float* xb = xT + (size_t)b * (64*64*256);
    f32x4_t vlt = (inxl && inyl) ? *(const f32x4_t*)&xb[((qlx-1)*64 + (qly-1))*256 + ic] : zero;
    f32x4_t vrb = (inxr && inyr) ? *(const f32x4_t*)&xb[((qrx-1)*64 + (qry-1))*256 + ic] : zero;
    f32x4_t vlb = (inxl && inyr) ? *(const f32x4_t*)&xb[((qlx-1)*64 + (qry-1))*256 + ic] : zero;
    f32x4_t vrt = (inxr && inyl) ? *(const f32x4_t*)&xb[((qrx-1)*64 + (qly-1))*256 + ic] : zero;
    ushort4 pk;
    float v0 = glt*vlt[0] + grb*vrb[0] + glb*vlb[0] + grt*vrt[0];
    float v1 = glt*vlt[1] + grb*vrb[1] + glb*vlb[1] + grt*vrt[1];
    float v2 = glt*vlt[2] + grb*vrb[2] + glb*vlb[2] + grt*vrt[2];
    float v3 = glt*vlt[3] + grb*vrb[3] + glb*vlb[3] + grt*vrt[3];
    pk.x = __hip_bfloat16_raw(__float2bfloat16(v0)).x;
    pk.y = __hip_bfloat16_raw(__float2bfloat16(v1)).x;
    pk.z = __hip_bfloat16_raw(__float2bfloat16(v2)).x;
    pk.w = __hip_bfloat16_raw(__float2bfloat16(v3)).x;
    *(ushort4*)&xoa[(((size_t)b*192 + i)*192 + j)*256 + ic] = pk;
  }
}

// ---------------------------------------------------------------------------
// conv: implicit GEMM.  grid.x = nab*144 blocks (XCD-swizzled).
// Per block: 256 px (4 rows x 64 cols) x 256 oc, K = 9 taps x 256 ic.
// BK=32 -> 72 K-tiles through a 4-deep LDS ring; vmcnt(4) counted waits.
// LDS: A: 4 bufs x 16 blocks x 1KB @0; B: same @65536; epilogue f32[128][258].
// ---------------------------------------------------------------------------
__global__ __launch_bounds__(512, 2) void k_conv2(
    const __hip_bfloat16* __restrict__ xo,   // [ab][192][192][256] bf16
    const __hip_bfloat16* __restrict__ wb,   // [9][256][256] bf16 (t,oc,ic)
    float* __restrict__ out)                 // + ab*9241600 : [256][190][190]
{
  extern __shared__ __align__(16) char smem[];
  const int nblk = gridDim.x;
  const int cpx = nblk >> 3;                 // nblk % 8 == 0 always
  const int sid = blockIdx.x;
  const int swz = (sid & 7)*cpx + (sid >> 3);
  const int ab = swz / 144;
  const int r144 = swz - ab*144;
  const int q  = r144 / 3;                   // 0..47 row-quad
  const int ct = r144 - q*3;                 // 0..2
  const int i0 = q*4, j0 = ct*64;

  const int tid = threadIdx.x;
  const int w  = tid >> 6;                   // wave 0..7
  const int l  = tid & 63;
  const int wm = w >> 2;                     // 0..1 (M half)
  const int wn = w & 3;                      // 0..3 (N quarter)

  const char* xob = (const char*)(xo + (size_t)ab * 9437184u);
  const char* wbc = (const char*)wb;

  // --- per-thread stage constants (lane l writes LDS slot l of its block) ---
  const int rA    = l >> 2;                               // row-in-block 0..15
  const int icoff = ((l & 3) ^ ((l >> 3) & 3)) * 8;       // ic elem offset in 32-group
  const int m0 = w*16 + rA,        m1 = (w+8)*16 + rA;    // A blocks w, w+8
  const int ia0 = i0 + (m0 >> 6),  ja0 = j0 + (m0 & 63);
  const int ia1 = i0 + (m1 >> 6),  ja1 = j0 + (m1 & 63);
  const int ocb0 = w*16 + rA,      ocb1 = (w+8)*16 + rA;  // B blocks w, w+8
  // frag-read lane offset within a 1KB block (bank-spread XOR layout)
  const int foff = ((l & 15)*4 + ((l >> 4) ^ ((l >> 1) & 3))) * 16;

  char* const sA = smem;                     // 4 x 16KB
  char* const sB = smem + 65536;             // 4 x 16KB

  auto stageA = [&](int kk) {
    const int t = kk >> 3, icg = kk & 7;
    const int ki = (t >= 6) ? 2 : ((t >= 3) ? 1 : 0);
    const int kj = t - ki*3;
    char* dst = sA + (kk & 3)*16384;
    int ra = ia0 + ki; ra = (ra > 191) ? 191 : ra;
    int ca = ja0 + kj; ca = (ca > 191) ? 191 : ca;
    gload16(xob + (size_t)(((ra*192 + ca) << 8) + icg*32 + icoff)*2, dst + w*1024);
    ra = ia1 + ki; ra = (ra > 191) ? 191 : ra;
    ca = ja1 + kj; ca = (ca > 191) ? 191 : ca;
    gload16(xob + (size_t)(((ra*192 + ca) << 8) + icg*32 + icoff)*2, dst + (w+8)*1024);
  };
  auto stageB = [&](int kk) {
    const int t = kk >> 3, icg = kk & 7;
    char* dst = sB + (kk & 3)*16384;
    const char* src = wbc + (size_t)((t << 16) + icg*32 + icoff)*2;
    gload16(src + ocb0*512, dst + w*1024);
    gload16(src + ocb1*512, dst + (w+8)*1024);
  };

  f32x4_t acc[8][4];
  #pragma unroll
  for (int mf = 0; mf < 8; ++mf)
    #pragma unroll
    for (int nf = 0; nf < 4; ++nf)
      acc[mf][nf] = (f32x4_t){0.f, 0.f, 0.f, 0.f};

  // prologue: tiles 0 and 1 in flight (per-thread issue order = tile order)
  stageA(0); stageB(0);
  stageA(1); stageB(1);

  for (int kk = 0; kk < 72; ++kk) {
    if (kk < 71) { asm volatile("s_waitcnt vmcnt(4)" ::: "memory"); }
    else         { asm volatile("s_waitcnt vmcnt(0)" ::: "memory"); }
    __builtin_amdgcn_s_barrier();
    __builtin_amdgcn_sched_barrier(0);

    const char* a_base = sA + (kk & 3)*16384;
    const char* b_base = sB + (kk & 3)*16384;

    // phase A: B-frags (whole tile) + A-frags m 0..3, stage A of tile kk+2
    bf16x8_t bfrg[4], afrg[4];
    #pragma unroll
    for (int nf = 0; nf < 4; ++nf)
      bfrg[nf] = *(const bf16x8_t*)(b_base + (wn*4 + nf)*1024 + foff);
    #pragma unroll
    for (int mf = 0; mf < 4; ++mf)
      afrg[mf] = *(const bf16x8_t*)(a_base + (wm*8 + mf)*1024 + foff);
    if (kk < 70) stageA(kk + 2);
    __builtin_amdgcn_s_setprio(1);
    #pragma unroll
    for (int mf = 0; mf < 4; ++mf)
      #pragma unroll
      for (int nf = 0; nf < 4; ++nf)
        acc[mf][nf] = __builtin_amdgcn_mfma_f32_16x16x32_bf16(
            afrg[mf], bfrg[nf], acc[mf][nf], 0, 0, 0);
    __builtin_amdgcn_s_setprio(0);

    // phase B: A-frags m 4..7, stage B of tile kk+2
    #pragma unroll
    for (int mf = 0; mf < 4; ++mf)
      afrg[mf] = *(const bf16x8_t*)(a_base + (wm*8 + 4 + mf)*1024 + foff);
    if (kk < 70) stageB(kk + 2);
    __builtin_amdgcn_s_setprio(1);
    #pragma unroll
    for (int mf = 0; mf < 4; ++mf)
      #pragma unroll
      for (int nf = 0; nf < 4; ++nf)
        acc[4 + mf][nf] = __builtin_amdgcn_mfma_f32_16x16x32_bf16(
            afrg[mf], bfrg[nf], acc[4 + mf][nf], 0, 0, 0);
    __builtin_amdgcn_s_setprio(0);
  }

  // --- epilogue: two oc-half passes through LDS f32[128][258] ---
  float* eps = (float*)smem;
  float* outab = out + (size_t)ab * 9241600u;
  const int ocr = tid >> 2;       // 0..127
  const int di  = tid & 3;
  const int iS  = i0 + di;
  const int jend = (j0 == 128) ? 62 : 64;

  #pragma unroll
  for (int h = 0; h < 2; ++h) {
    __syncthreads();
    if ((wn >> 1) == h) {
      #pragma unroll
      for (int mf = 0; mf < 8; ++mf)
        #pragma unroll
        for (int nf = 0; nf < 4; ++nf)
          #pragma unroll
          for (int v = 0; v < 4; ++v)
            eps[((wn & 1)*64 + nf*16 + (l & 15))*258 +
                wm*128 + mf*16 + (l >> 4)*4 + v] = acc[mf][nf][v];
    }
    __syncthreads();
    if (iS < 190) {
      float* dst = outab + (size_t)(h*128 + ocr)*36100u + iS*190 + j0;
      const float* src = eps + ocr*258 + di*64;
      for (int jc = 0; jc < jend; jc += 2)
        *(float2*)(dst + jc) = make_float2(src[jc], src[jc + 1]);
    }
  }
}

extern "C" void kernel_launch(void* const* d_in, const int* in_sizes, int n_in,
                              void* d_out, int out_size, void* d_ws, size_t ws_size,
                              hipStream_t stream)
{
  const float* x = (const float*)d_in[0];
  const float* w = (const float*)d_in[1];
  float* out = (float*)d_out;

  char* ws = (char*)d_ws;
  float*          xT = (float*)ws;                         // 8,388,608 B
  __hip_bfloat16* wb = (__hip_bfloat16*)(ws + 8388608);    // 1,179,648 B
  __hip_bfloat16* xo = (__hip_bfloat16*)(ws + 9568256);    // 5 or 1 x 37,748,736 B

  const bool merged = (ws_size >= 198311936ull);

  (void)hipFuncSetAttribute((const void*)k_conv2,
                            hipFuncAttributeMaxDynamicSharedMemorySize, 132096);

  k_transpose<<<dim3(64, 64, 2), 256, 0, stream>>>(x, xT);
  k_wconv<<<2304, 256, 0, stream>>>(w, wb);

  if (merged) {
    k_sample<<<dim3(48, 192, 5), 256, 0, stream>>>(xT, xo, 0);
    k_conv2<<<1440, 512, 132096, stream>>>(xo, wb, out);
  } else {
    for (int aidx = 0; aidx < 5; ++aidx) {
      k_sample<<<dim3(48, 192, 1), 256, 0, stream>>>(xT, xo, aidx);
      k_conv2<<<288, 512, 132096, stream>>>(xo, wb, out + (size_t)aidx * 18483200u);
    }
  }
}